// Round 5
// baseline (1492.824 us; speedup 1.0000x reference)
//
#include <hip/hip_runtime.h>
#include <hip/hip_bf16.h>

typedef unsigned char u8;
typedef unsigned short u16;
typedef unsigned int u32;
typedef __attribute__((ext_vector_type(4))) int intx4;
typedef __attribute__((ext_vector_type(8))) int intx8;
typedef __attribute__((ext_vector_type(4))) float floatx4;

#define NPIX 12544   // 112*112 = 98 * 128
#define KDIM 768     // channels; fp8 row = 768 B
#define EPSF 1e-8f
#define SCALE1 0x7F7F7F7FU  // E8M0 = 127 -> 2^0 = 1.0 in every byte

// ---------------------------------------------------------------- async G->LDS
__device__ __forceinline__ void gload_lds16(const void* g, void* l) {
  __builtin_amdgcn_global_load_lds(
      (const __attribute__((address_space(1))) void*)g,
      (__attribute__((address_space(3))) void*)l, 16, 0, 0);
}

// sortable-uint encoding of float (monotone): max over enc == max over float
__device__ __forceinline__ u32 enc_f32(float f) {
  u32 u = __float_as_uint(f);
  return (u & 0x80000000u) ? ~u : (u | 0x80000000u);
}
__device__ __forceinline__ float dec_f32(u32 e) {
  u32 u = (e & 0x80000000u) ? (e & 0x7FFFFFFFu) : ~e;
  return __uint_as_float(u);
}

// ---------------------------------------------------------------- K1: column sum-of-squares partials
__global__ void colsumsq_kernel(const float* __restrict__ a, const float* __restrict__ b,
                                float* __restrict__ pa, float* __restrict__ pb) {
  int i = blockIdx.x * 256 + threadIdx.x;
  int c0 = blockIdx.y * 96;
  float sa = 0.f, sb = 0.f;
#pragma unroll 4
  for (int c = c0; c < c0 + 96; ++c) {
    float va = a[(size_t)c * NPIX + i];
    float vb = b[(size_t)c * NPIX + i];
    sa += va * va;
    sb += vb * vb;
  }
  pa[(size_t)blockIdx.y * NPIX + i] = sa;
  pb[(size_t)blockIdx.y * NPIX + i] = sb;
}

// ---------------------------------------------------------------- K2: 1/(sqrt(sum+eps)+eps) + zero atomic-max buffer
__global__ void rnorm_kernel(const float* __restrict__ pa, const float* __restrict__ pb,
                             float* __restrict__ ra, float* __restrict__ rb,
                             u32* __restrict__ part) {
  int i = blockIdx.x * 256 + threadIdx.x;
  float sa = 0.f, sb = 0.f;
#pragma unroll
  for (int c = 0; c < 8; ++c) {
    sa += pa[(size_t)c * NPIX + i];
    sb += pb[(size_t)c * NPIX + i];
  }
  ra[i] = 1.f / (sqrtf(sa + EPSF) + EPSF);
  rb[i] = 1.f / (sqrtf(sb + EPSF) + EPSF);
  part[i] = 0u;
}

// ---------------------------------------------------------------- K3: transpose + normalize + fp8 e4m3 pack
__global__ void transpose_kernel(const float* __restrict__ a, const float* __restrict__ b,
                                 const float* __restrict__ ra, const float* __restrict__ rb,
                                 u8* __restrict__ Ar, u8* __restrict__ Br) {
  const float* src = blockIdx.z ? b : a;
  const float* rn  = blockIdx.z ? rb : ra;
  u8* dst          = blockIdx.z ? Br : Ar;
  __shared__ float tile[32][33];
  int i0 = blockIdx.x * 32;
  int c0 = blockIdx.y * 32;
  int tx = threadIdx.x & 31;
  int ty = threadIdx.x >> 5;
#pragma unroll
  for (int d = 0; d < 4; ++d) {
    int c = c0 + ty + d * 8;
    tile[ty + d * 8][tx] = src[(size_t)c * NPIX + i0 + tx];
  }
  __syncthreads();
  int pl = threadIdx.x >> 3;
  int cq = threadIdx.x & 7;
  int gi = i0 + pl;
  float r = rn[gi];
  float v0 = tile[cq * 4 + 0][pl] * r;
  float v1 = tile[cq * 4 + 1][pl] * r;
  float v2 = tile[cq * 4 + 2][pl] * r;
  float v3 = tile[cq * 4 + 3][pl] * r;
  int p = __builtin_amdgcn_cvt_pk_fp8_f32(v0, v1, 0, false);
  p = __builtin_amdgcn_cvt_pk_fp8_f32(v2, v3, p, true);
  *(u32*)&dst[(size_t)gi * KDIM + c0 + cq * 4] = (u32)p;
}

// ---------------------------------------------------------------- K4: 128x128 tile per block, MX-fp8 K=128
// LDS per matrix: 2 K-halves (h=0,1), each 128 rows x 64 B. Logical 16B chunk c
// (k bytes h*64+c*16..+16) of row R stored at slot (c + (R>>1) + h)&3
// -> per-quad slot rotations {0,2,1,3}: R3's measured-zero bank pattern.
__global__ __launch_bounds__(256, 4) void gemm_max_kernel(const u8* __restrict__ Ar,
                                                          const u8* __restrict__ Br,
                                                          u32* __restrict__ part) {
  const int X = blockIdx.x;
  const int t13 = blockIdx.y;
  const int live = (X < 2) ? 13 : 12;
  if (t13 >= live) return;
  const int ct = (X < 2) ? (X * 13 + t13) : (X * 12 + 2 + t13);
  const int rt = blockIdx.z;

  __shared__ alignas(16) u8 As[16384];
  __shared__ alignas(16) u8 Bs[16384];
  __shared__ float s_max[2 * 128];

  const int tid = threadIdx.x;
  const int wave = tid >> 6;
  const int lane = tid & 63;
  const int wx = wave & 1;
  const int wy = wave >> 1;
  const int l15 = lane & 15;
  const int quad = lane >> 4;

  const int row_base = rt * 128;
  const int col_base = ct * 128;

  // block-uniform bases (SGPR)
  const u8* gA = Ar + (size_t)row_base * KDIM;
  const u8* gB = Br + (size_t)col_base * KDIM;

  // staging: instr (t,h): thread tid covers slot_idx = t*256+tid ->
  // row R = slot_idx>>2, slot s = slot_idx&3, chunk c = (s - (R>>1) - h)&3;
  // src off = R*KDIM + h*64 + c*16; LDS dest = half h*8192 + t*4096 + tid*16
  int soff[2][2];
#pragma unroll
  for (int t = 0; t < 2; ++t)
#pragma unroll
    for (int h = 0; h < 2; ++h) {
      int si = t * 256 + tid;
      int R = si >> 2;
      int s = si & 3;
      int c = (s - (R >> 1) - h) & 3;
      soff[t][h] = R * KDIM + h * 64 + c * 16;
    }

  // fragment read addresses (k-invariant; mf/nf adds 16 rows = +1024 B)
  const int h = quad >> 1;
  const int c0 = (quad & 1) * 2;
  const int Ra = wy * 64 + l15;
  const int Rb = wx * 64 + l15;
  const int sa0 = (c0 + (Ra >> 1) + h) & 3;
  const int sa1 = (c0 + 1 + (Ra >> 1) + h) & 3;
  const int sb0 = (c0 + (Rb >> 1) + h) & 3;
  const int sb1 = (c0 + 1 + (Rb >> 1) + h) & 3;
  const u8* aAd0 = &As[h * 8192 + Ra * 64 + sa0 * 16];
  const u8* aAd1 = &As[h * 8192 + Ra * 64 + sa1 * 16];
  const u8* bAd0 = &Bs[h * 8192 + Rb * 64 + sb0 * 16];
  const u8* bAd1 = &Bs[h * 8192 + Rb * 64 + sb1 * 16];

  floatx4 acc[4][4];
#pragma unroll
  for (int mf = 0; mf < 4; ++mf)
#pragma unroll
    for (int nf = 0; nf < 4; ++nf) acc[mf][nf] = (floatx4){0.f, 0.f, 0.f, 0.f};

  for (int k0 = 0; k0 < KDIM; k0 += 128) {
    __syncthreads();
#pragma unroll
    for (int t = 0; t < 2; ++t)
#pragma unroll
      for (int hh = 0; hh < 2; ++hh) {
        gload_lds16(gA + soff[t][hh] + k0, &As[hh * 8192 + t * 4096 + tid * 16]);
        gload_lds16(gB + soff[t][hh] + k0, &Bs[hh * 8192 + t * 4096 + tid * 16]);
      }
    __syncthreads();

    intx8 afr[4];
#pragma unroll
    for (int mf = 0; mf < 4; ++mf) {
      intx4 lo = *(const intx4*)(aAd0 + mf * 1024);
      intx4 hi = *(const intx4*)(aAd1 + mf * 1024);
      intx8 f;
      f[0] = lo[0]; f[1] = lo[1]; f[2] = lo[2]; f[3] = lo[3];
      f[4] = hi[0]; f[5] = hi[1]; f[6] = hi[2]; f[7] = hi[3];
      afr[mf] = f;
    }
#pragma unroll
    for (int nf = 0; nf < 4; ++nf) {
      intx4 lo = *(const intx4*)(bAd0 + nf * 1024);
      intx4 hi = *(const intx4*)(bAd1 + nf * 1024);
      intx8 bfr;
      bfr[0] = lo[0]; bfr[1] = lo[1]; bfr[2] = lo[2]; bfr[3] = lo[3];
      bfr[4] = hi[0]; bfr[5] = hi[1]; bfr[6] = hi[2]; bfr[7] = hi[3];
#pragma unroll
      for (int mf = 0; mf < 4; ++mf)
        acc[mf][nf] = __builtin_amdgcn_mfma_scale_f32_16x16x128_f8f6f4(
            afr[mf], bfr, acc[mf][nf], 0, 0, 0, SCALE1, 0, SCALE1);
    }
  }

  // epilogue: per-row max; C layout: col = l15 (+nf*16), row = quad*4 + r (+mf*16)
#pragma unroll
  for (int mf = 0; mf < 4; ++mf) {
#pragma unroll
    for (int r = 0; r < 4; ++r) {
      float best = acc[mf][0][r];
      best = fmaxf(best, acc[mf][1][r]);
      best = fmaxf(best, acc[mf][2][r]);
      best = fmaxf(best, acc[mf][3][r]);
      best = fmaxf(best, __shfl_xor(best, 1));
      best = fmaxf(best, __shfl_xor(best, 2));
      best = fmaxf(best, __shfl_xor(best, 4));
      best = fmaxf(best, __shfl_xor(best, 8));
      if (l15 == 0) {
        int row = wy * 64 + mf * 16 + quad * 4 + r;
        s_max[wx * 128 + row] = best;
      }
    }
  }
  __syncthreads();
  if (tid < 128) {
    float m = fmaxf(s_max[tid], s_max[128 + tid]);
    atomicMax(&part[row_base + tid], enc_f32(m));
  }
}

// ---------------------------------------------------------------- K5: decode + loss (fp32 scalar out)
__global__ void finish_kernel(const u32* __restrict__ part, float* __restrict__ out) {
  float v = 0.f;
  for (int i = threadIdx.x; i < NPIX; i += 1024) {
    v += 1.0f - dec_f32(part[i]);
  }
#pragma unroll
  for (int off = 32; off > 0; off >>= 1) v += __shfl_down(v, off);
  __shared__ float red[16];
  int w = threadIdx.x >> 6;
  if ((threadIdx.x & 63) == 0) red[w] = v;
  __syncthreads();
  if (threadIdx.x == 0) {
    float s = 0.f;
#pragma unroll
    for (int k = 0; k < 16; ++k) s += red[k];
    out[0] = s * (1.0f / (float)NPIX);
  }
}

// ---------------------------------------------------------------- launcher
extern "C" void kernel_launch(void* const* d_in, const int* in_sizes, int n_in,
                              void* d_out, int out_size, void* d_ws, size_t ws_size,
                              hipStream_t stream) {
  const float* x = (const float*)d_in[0];
  const float* s = (const float*)d_in[1];
  char* ws = (char*)d_ws;
  float* pa   = (float*)(ws + 0);         //   401408
  float* pb   = (float*)(ws + 401408);    //   401408
  float* ra   = (float*)(ws + 802816);    //    50176
  float* rb   = (float*)(ws + 852992);    //    50176
  u32*   part = (u32*)  (ws + 903168);    //    50176 (encoded row maxima)
  u8*    Ar   = (u8*)   (ws + 953344);    //  9633792
  u8*    Br   = (u8*)   (ws + 10587136);  //  9633792  -> total 20220928 B

  colsumsq_kernel<<<dim3(49, 8), 256, 0, stream>>>(x, s, pa, pb);
  rnorm_kernel<<<49, 256, 0, stream>>>(pa, pb, ra, rb, part);
  transpose_kernel<<<dim3(392, 24, 2), 256, 0, stream>>>(x, s, ra, rb, Ar, Br);
  gemm_max_kernel<<<dim3(8, 13, 98), 256, 0, stream>>>(Ar, Br, part);
  finish_kernel<<<1, 1024, 0, stream>>>(part, (float*)d_out);
}

// Round 6
// 1198.342 us; speedup vs baseline: 1.2457x; 1.2457x over previous
//
#include <hip/hip_runtime.h>
#include <hip/hip_bf16.h>

typedef unsigned char u8;
typedef unsigned short u16;
typedef unsigned int u32;
typedef __attribute__((ext_vector_type(4))) int intx4;
typedef __attribute__((ext_vector_type(8))) int intx8;
typedef __attribute__((ext_vector_type(4))) float floatx4;

#define NPIX 12544   // 112*112 = 98 * 128
#define KDIM 768     // channels; fp8 row = 768 B
#define EPSF 1e-8f
#define SCALE1 0x7F7F7F7FU  // E8M0 = 127 -> 2^0 = 1.0 in every byte

// ---------------------------------------------------------------- async G->LDS
__device__ __forceinline__ void gload_lds16(const void* g, void* l) {
  __builtin_amdgcn_global_load_lds(
      (const __attribute__((address_space(1))) void*)g,
      (__attribute__((address_space(3))) void*)l, 16, 0, 0);
}

// sortable-uint encoding of float (monotone): max over enc == max over float
__device__ __forceinline__ u32 enc_f32(float f) {
  u32 u = __float_as_uint(f);
  return (u & 0x80000000u) ? ~u : (u | 0x80000000u);
}
__device__ __forceinline__ float dec_f32(u32 e) {
  u32 u = (e & 0x80000000u) ? (e & 0x7FFFFFFFu) : ~e;
  return __uint_as_float(u);
}

// ---------------------------------------------------------------- K1: column sum-of-squares partials
__global__ void colsumsq_kernel(const float* __restrict__ a, const float* __restrict__ b,
                                float* __restrict__ pa, float* __restrict__ pb) {
  int i = blockIdx.x * 256 + threadIdx.x;
  int c0 = blockIdx.y * 96;
  float sa = 0.f, sb = 0.f;
#pragma unroll 4
  for (int c = c0; c < c0 + 96; ++c) {
    float va = a[(size_t)c * NPIX + i];
    float vb = b[(size_t)c * NPIX + i];
    sa += va * va;
    sb += vb * vb;
  }
  pa[(size_t)blockIdx.y * NPIX + i] = sa;
  pb[(size_t)blockIdx.y * NPIX + i] = sb;
}

// ---------------------------------------------------------------- K2: 1/(sqrt(sum+eps)+eps) + zero atomic-max buffer
__global__ void rnorm_kernel(const float* __restrict__ pa, const float* __restrict__ pb,
                             float* __restrict__ ra, float* __restrict__ rb,
                             u32* __restrict__ part) {
  int i = blockIdx.x * 256 + threadIdx.x;
  float sa = 0.f, sb = 0.f;
#pragma unroll
  for (int c = 0; c < 8; ++c) {
    sa += pa[(size_t)c * NPIX + i];
    sb += pb[(size_t)c * NPIX + i];
  }
  ra[i] = 1.f / (sqrtf(sa + EPSF) + EPSF);
  rb[i] = 1.f / (sqrtf(sb + EPSF) + EPSF);
  part[i] = 0u;
}

// ---------------------------------------------------------------- K3: transpose + normalize + fp8 e4m3 pack
__global__ void transpose_kernel(const float* __restrict__ a, const float* __restrict__ b,
                                 const float* __restrict__ ra, const float* __restrict__ rb,
                                 u8* __restrict__ Ar, u8* __restrict__ Br) {
  const float* src = blockIdx.z ? b : a;
  const float* rn  = blockIdx.z ? rb : ra;
  u8* dst          = blockIdx.z ? Br : Ar;
  __shared__ float tile[32][33];
  int i0 = blockIdx.x * 32;
  int c0 = blockIdx.y * 32;
  int tx = threadIdx.x & 31;
  int ty = threadIdx.x >> 5;
#pragma unroll
  for (int d = 0; d < 4; ++d) {
    int c = c0 + ty + d * 8;
    tile[ty + d * 8][tx] = src[(size_t)c * NPIX + i0 + tx];
  }
  __syncthreads();
  int pl = threadIdx.x >> 3;
  int cq = threadIdx.x & 7;
  int gi = i0 + pl;
  float r = rn[gi];
  float v0 = tile[cq * 4 + 0][pl] * r;
  float v1 = tile[cq * 4 + 1][pl] * r;
  float v2 = tile[cq * 4 + 2][pl] * r;
  float v3 = tile[cq * 4 + 3][pl] * r;
  int p = __builtin_amdgcn_cvt_pk_fp8_f32(v0, v1, 0, false);
  p = __builtin_amdgcn_cvt_pk_fp8_f32(v2, v3, p, true);
  *(u32*)&dst[(size_t)gi * KDIM + c0 + cq * 4] = (u32)p;
}

// ---------------------------------------------------------------- K4: 128x128 tile per block, MX-fp8 K=128
// LDS layout (per matrix, 16 KB): 8 groups of 16 rows. Group g (2048 B) =
// LO 1024 B (chunks c=2q: bytes q*32..+15 of each row) then HI 1024 B
// (chunks c=2q+1). Within a half, chunk of (row r16, quad q) at q*256+r16*16.
// => every fragment ds_read_b128 is identity-permutation over a contiguous
// 1024 B region (R3's measured-zero conflict property), and fragment
// addresses are one per-lane base + immediate offsets.
__global__ __launch_bounds__(256, 3) void gemm_max_kernel(const u8* __restrict__ Ar,
                                                          const u8* __restrict__ Br,
                                                          u32* __restrict__ part) {
  const int X = blockIdx.x;
  const int t13 = blockIdx.y;
  const int live = (X < 2) ? 13 : 12;
  if (t13 >= live) return;
  const int ct = (X < 2) ? (X * 13 + t13) : (X * 12 + 2 + t13);
  const int rt = blockIdx.z;

  __shared__ alignas(16) u8 As[16384];
  __shared__ alignas(16) u8 Bs[16384];
  __shared__ float s_max[2 * 128];

  const int tid = threadIdx.x;
  const int wave = tid >> 6;
  const int lane = tid & 63;
  const int wx = wave & 1;
  const int wy = wave >> 1;
  const int l15 = lane & 15;
  const int quad = lane >> 4;

  const int row_base = rt * 128;
  const int col_base = ct * 128;

  // block-uniform global bases (SGPR)
  const u8* gA = Ar + (size_t)row_base * KDIM;
  const u8* gB = Br + (size_t)col_base * KDIM;

  // staging: instr t writes dest bytes D = t*4096 + tid*16. Decode D ->
  // (g, hi, q, r16) -> source offset (g*16+r16)*KDIM + (2q+hi)*16.
  int soff[4];
#pragma unroll
  for (int t = 0; t < 4; ++t) {
    int D = t * 4096 + tid * 16;
    int g = D >> 11;
    int hi = (D >> 10) & 1;
    int q = (D >> 8) & 3;
    int r16 = (D >> 4) & 15;
    soff[t] = (g * 16 + r16) * KDIM + (2 * q + hi) * 16;
  }

  // fragment bases: group g = wy*4+mf (A) / wx*4+nf (B); per-lane base covers
  // (quad, l15); mf/nf stride = 2048 B immediate, HI at +1024.
  const u8* aP = &As[wy * 8192 + quad * 256 + l15 * 16];
  const u8* bP = &Bs[wx * 8192 + quad * 256 + l15 * 16];

  floatx4 acc[4][4];
#pragma unroll
  for (int mf = 0; mf < 4; ++mf)
#pragma unroll
    for (int nf = 0; nf < 4; ++nf) acc[mf][nf] = (floatx4){0.f, 0.f, 0.f, 0.f};

  for (int k0 = 0; k0 < KDIM; k0 += 128) {
    __syncthreads();
#pragma unroll
    for (int t = 0; t < 4; ++t) {
      gload_lds16(gA + soff[t] + k0, &As[t * 4096 + tid * 16]);
      gload_lds16(gB + soff[t] + k0, &Bs[t * 4096 + tid * 16]);
    }
    __syncthreads();

    intx8 afr[4];
#pragma unroll
    for (int mf = 0; mf < 4; ++mf) {
      intx4 lo = *(const intx4*)(aP + mf * 2048);
      intx4 hi = *(const intx4*)(aP + mf * 2048 + 1024);
      intx8 f;
      f[0] = lo[0]; f[1] = lo[1]; f[2] = lo[2]; f[3] = lo[3];
      f[4] = hi[0]; f[5] = hi[1]; f[6] = hi[2]; f[7] = hi[3];
      afr[mf] = f;
    }
#pragma unroll
    for (int nf = 0; nf < 4; ++nf) {
      intx4 lo = *(const intx4*)(bP + nf * 2048);
      intx4 hi = *(const intx4*)(bP + nf * 2048 + 1024);
      intx8 bfr;
      bfr[0] = lo[0]; bfr[1] = lo[1]; bfr[2] = lo[2]; bfr[3] = lo[3];
      bfr[4] = hi[0]; bfr[5] = hi[1]; bfr[6] = hi[2]; bfr[7] = hi[3];
#pragma unroll
      for (int mf = 0; mf < 4; ++mf)
        acc[mf][nf] = __builtin_amdgcn_mfma_scale_f32_16x16x128_f8f6f4(
            afr[mf], bfr, acc[mf][nf], 0, 0, 0, SCALE1, 0, SCALE1);
    }
  }

  // epilogue: per-row max; C layout: col = l15 (+nf*16), row = quad*4 + r (+mf*16)
#pragma unroll
  for (int mf = 0; mf < 4; ++mf) {
#pragma unroll
    for (int r = 0; r < 4; ++r) {
      float best = acc[mf][0][r];
      best = fmaxf(best, acc[mf][1][r]);
      best = fmaxf(best, acc[mf][2][r]);
      best = fmaxf(best, acc[mf][3][r]);
      best = fmaxf(best, __shfl_xor(best, 1));
      best = fmaxf(best, __shfl_xor(best, 2));
      best = fmaxf(best, __shfl_xor(best, 4));
      best = fmaxf(best, __shfl_xor(best, 8));
      if (l15 == 0) {
        int row = wy * 64 + mf * 16 + quad * 4 + r;
        s_max[wx * 128 + row] = best;
      }
    }
  }
  __syncthreads();
  if (tid < 128) {
    float m = fmaxf(s_max[tid], s_max[128 + tid]);
    atomicMax(&part[row_base + tid], enc_f32(m));
  }
}

// ---------------------------------------------------------------- K5: decode + loss (fp32 scalar out)
__global__ void finish_kernel(const u32* __restrict__ part, float* __restrict__ out) {
  float v = 0.f;
  for (int i = threadIdx.x; i < NPIX; i += 1024) {
    v += 1.0f - dec_f32(part[i]);
  }
#pragma unroll
  for (int off = 32; off > 0; off >>= 1) v += __shfl_down(v, off);
  __shared__ float red[16];
  int w = threadIdx.x >> 6;
  if ((threadIdx.x & 63) == 0) red[w] = v;
  __syncthreads();
  if (threadIdx.x == 0) {
    float s = 0.f;
#pragma unroll
    for (int k = 0; k < 16; ++k) s += red[k];
    out[0] = s * (1.0f / (float)NPIX);
  }
}

// ---------------------------------------------------------------- launcher
extern "C" void kernel_launch(void* const* d_in, const int* in_sizes, int n_in,
                              void* d_out, int out_size, void* d_ws, size_t ws_size,
                              hipStream_t stream) {
  const float* x = (const float*)d_in[0];
  const float* s = (const float*)d_in[1];
  char* ws = (char*)d_ws;
  float* pa   = (float*)(ws + 0);         //   401408
  float* pb   = (float*)(ws + 401408);    //   401408
  float* ra   = (float*)(ws + 802816);    //    50176
  float* rb   = (float*)(ws + 852992);    //    50176
  u32*   part = (u32*)  (ws + 903168);    //    50176 (encoded row maxima)
  u8*    Ar   = (u8*)   (ws + 953344);    //  9633792
  u8*    Br   = (u8*)   (ws + 10587136);  //  9633792  -> total 20220928 B

  colsumsq_kernel<<<dim3(49, 8), 256, 0, stream>>>(x, s, pa, pb);
  rnorm_kernel<<<49, 256, 0, stream>>>(pa, pb, ra, rb, part);
  transpose_kernel<<<dim3(392, 24, 2), 256, 0, stream>>>(x, s, ra, rb, Ar, Br);
  gemm_max_kernel<<<dim3(8, 13, 98), 256, 0, stream>>>(Ar, Br, part);
  finish_kernel<<<1, 1024, 0, stream>>>(part, (float*)d_out);
}

// Round 7
// 772.925 us; speedup vs baseline: 1.9314x; 1.5504x over previous
//
#include <hip/hip_runtime.h>
#include <hip/hip_bf16.h>

typedef unsigned char u8;
typedef unsigned short u16;
typedef unsigned int u32;
typedef __attribute__((ext_vector_type(4))) int intx4;
typedef __attribute__((ext_vector_type(8))) int intx8;
typedef __attribute__((ext_vector_type(4))) float floatx4;
typedef __attribute__((ext_vector_type(16))) float floatx16;

#define NPIX 12544   // 112*112 = 98 * 128
#define KDIM 768     // channels; fp8 row = 768 B
#define EPSF 1e-8f
#define SCALE1 0x7F7F7F7FU  // E8M0 = 127 -> 2^0 = 1.0 in every byte

// ---------------------------------------------------------------- async G->LDS
__device__ __forceinline__ void gload_lds16(const void* g, void* l) {
  __builtin_amdgcn_global_load_lds(
      (const __attribute__((address_space(1))) void*)g,
      (__attribute__((address_space(3))) void*)l, 16, 0, 0);
}

// sortable-uint encoding of float (monotone): max over enc == max over float
__device__ __forceinline__ u32 enc_f32(float f) {
  u32 u = __float_as_uint(f);
  return (u & 0x80000000u) ? ~u : (u | 0x80000000u);
}
__device__ __forceinline__ float dec_f32(u32 e) {
  u32 u = (e & 0x80000000u) ? (e & 0x7FFFFFFFu) : ~e;
  return __uint_as_float(u);
}

// ---------------------------------------------------------------- K1: column sum-of-squares partials
__global__ void colsumsq_kernel(const float* __restrict__ a, const float* __restrict__ b,
                                float* __restrict__ pa, float* __restrict__ pb) {
  int i = blockIdx.x * 256 + threadIdx.x;
  int c0 = blockIdx.y * 96;
  float sa = 0.f, sb = 0.f;
#pragma unroll 4
  for (int c = c0; c < c0 + 96; ++c) {
    float va = a[(size_t)c * NPIX + i];
    float vb = b[(size_t)c * NPIX + i];
    sa += va * va;
    sb += vb * vb;
  }
  pa[(size_t)blockIdx.y * NPIX + i] = sa;
  pb[(size_t)blockIdx.y * NPIX + i] = sb;
}

// ---------------------------------------------------------------- K2: 1/(sqrt(sum+eps)+eps) + zero atomic-max buffer
__global__ void rnorm_kernel(const float* __restrict__ pa, const float* __restrict__ pb,
                             float* __restrict__ ra, float* __restrict__ rb,
                             u32* __restrict__ part) {
  int i = blockIdx.x * 256 + threadIdx.x;
  float sa = 0.f, sb = 0.f;
#pragma unroll
  for (int c = 0; c < 8; ++c) {
    sa += pa[(size_t)c * NPIX + i];
    sb += pb[(size_t)c * NPIX + i];
  }
  ra[i] = 1.f / (sqrtf(sa + EPSF) + EPSF);
  rb[i] = 1.f / (sqrtf(sb + EPSF) + EPSF);
  part[i] = 0u;
}

// ---------------------------------------------------------------- K3: transpose + normalize + fp8 e4m3 pack
__global__ void transpose_kernel(const float* __restrict__ a, const float* __restrict__ b,
                                 const float* __restrict__ ra, const float* __restrict__ rb,
                                 u8* __restrict__ Ar, u8* __restrict__ Br) {
  const float* src = blockIdx.z ? b : a;
  const float* rn  = blockIdx.z ? rb : ra;
  u8* dst          = blockIdx.z ? Br : Ar;
  __shared__ float tile[32][33];
  int i0 = blockIdx.x * 32;
  int c0 = blockIdx.y * 32;
  int tx = threadIdx.x & 31;
  int ty = threadIdx.x >> 5;
#pragma unroll
  for (int d = 0; d < 4; ++d) {
    int c = c0 + ty + d * 8;
    tile[ty + d * 8][tx] = src[(size_t)c * NPIX + i0 + tx];
  }
  __syncthreads();
  int pl = threadIdx.x >> 3;
  int cq = threadIdx.x & 7;
  int gi = i0 + pl;
  float r = rn[gi];
  float v0 = tile[cq * 4 + 0][pl] * r;
  float v1 = tile[cq * 4 + 1][pl] * r;
  float v2 = tile[cq * 4 + 2][pl] * r;
  float v3 = tile[cq * 4 + 3][pl] * r;
  int p = __builtin_amdgcn_cvt_pk_fp8_f32(v0, v1, 0, false);
  p = __builtin_amdgcn_cvt_pk_fp8_f32(v2, v3, p, true);
  *(u32*)&dst[(size_t)gi * KDIM + c0 + cq * 4] = (u32)p;
}

// ---------------------------------------------------------------- K4: 128x128 tile per block, MX-fp8 32x32x64
// Wave (wx,wy) computes 64x64 as 2x2 tiles of 32x32 (K=64 per mfma).
// LDS (per matrix, 16 KB): 8 regions of 2048 B = (32-row group rg, k64 block kb).
// Byte (row r, k: h=k>>5, c=(k>>4)&1, j=k&15) at region + c*1024 + (h*32+r)*16 + j.
// A-operand layout: lane = (k-half h = lane>>5, row = lane&31), 32 contiguous
// K-bytes/lane -> each frag b128 is the identity permutation over one
// contiguous 1024 B region (R6-verified zero-conflict property).
__global__ __launch_bounds__(256, 3) void gemm_max_kernel(const u8* __restrict__ Ar,
                                                          const u8* __restrict__ Br,
                                                          u32* __restrict__ part) {
  const int X = blockIdx.x;
  const int t13 = blockIdx.y;
  const int live = (X < 2) ? 13 : 12;
  if (t13 >= live) return;
  const int ct = (X < 2) ? (X * 13 + t13) : (X * 12 + 2 + t13);
  const int rt = blockIdx.z;

  __shared__ alignas(16) u8 As[16384];
  __shared__ alignas(16) u8 Bs[16384];
  __shared__ float s_max[2 * 128];

  const int tid = threadIdx.x;
  const int wave = tid >> 6;
  const int lane = tid & 63;
  const int wx = wave & 1;
  const int wy = wave >> 1;
  const int lh = lane >> 5;   // k-half within fragment ops
  const int l31 = lane & 31;

  const int row_base = rt * 128;
  const int col_base = ct * 128;

  const u8* gA = Ar + (size_t)row_base * KDIM;
  const u8* gB = Br + (size_t)col_base * KDIM;

  // staging: instr t writes LDS bytes D = t*4096 + tid*16; decode D ->
  // region = D>>11 (rg = region>>1, kb = region&1), w = D&2047:
  // c = w>>10, h = (w>>9)&1... (w>>4)&63 = h*32+r
  int soff[4];
#pragma unroll
  for (int t = 0; t < 4; ++t) {
    int D = t * 4096 + tid * 16;
    int rg = D >> 12;
    int kb = (D >> 11) & 1;
    int w = D & 2047;
    int c = w >> 10;
    int hr = (w >> 4) & 63;
    int h = hr >> 5;
    int r = hr & 31;
    soff[t] = (rg * 32 + r) * KDIM + kb * 64 + h * 32 + c * 16;
  }

  // fragment per-lane bases; offsets: mf/nf*4096 + s*2048 + {0,1024}
  const u8* aP = &As[wy * 8192 + lane * 16];
  const u8* bP = &Bs[wx * 8192 + lane * 16];

  floatx16 acc[2][2];
#pragma unroll
  for (int mf = 0; mf < 2; ++mf)
#pragma unroll
    for (int nf = 0; nf < 2; ++nf)
#pragma unroll
      for (int i = 0; i < 16; ++i) acc[mf][nf][i] = 0.f;

  for (int k0 = 0; k0 < KDIM; k0 += 128) {
    __syncthreads();
#pragma unroll
    for (int t = 0; t < 4; ++t) {
      gload_lds16(gA + soff[t] + k0, &As[t * 4096 + tid * 16]);
      gload_lds16(gB + soff[t] + k0, &Bs[t * 4096 + tid * 16]);
    }
    __syncthreads();

#pragma unroll
    for (int s = 0; s < 2; ++s) {
      intx8 af[2];
#pragma unroll
      for (int mf = 0; mf < 2; ++mf) {
        intx4 lo = *(const intx4*)(aP + mf * 4096 + s * 2048);
        intx4 hi = *(const intx4*)(aP + mf * 4096 + s * 2048 + 1024);
        intx8 f;
        f[0] = lo[0]; f[1] = lo[1]; f[2] = lo[2]; f[3] = lo[3];
        f[4] = hi[0]; f[5] = hi[1]; f[6] = hi[2]; f[7] = hi[3];
        af[mf] = f;
      }
#pragma unroll
      for (int nf = 0; nf < 2; ++nf) {
        intx4 lo = *(const intx4*)(bP + nf * 4096 + s * 2048);
        intx4 hi = *(const intx4*)(bP + nf * 4096 + s * 2048 + 1024);
        intx8 bf;
        bf[0] = lo[0]; bf[1] = lo[1]; bf[2] = lo[2]; bf[3] = lo[3];
        bf[4] = hi[0]; bf[5] = hi[1]; bf[6] = hi[2]; bf[7] = hi[3];
#pragma unroll
        for (int mf = 0; mf < 2; ++mf)
          acc[mf][nf] = __builtin_amdgcn_mfma_scale_f32_32x32x64_f8f6f4(
              af[mf], bf, acc[mf][nf], 0, 0, 0, SCALE1, 0, SCALE1);
      }
    }
  }

  // epilogue: per-row max. 32x32 C/D layout: col = lane&31,
  // row = (reg&3) + 8*(reg>>2) + 4*(lane>>5).
#pragma unroll
  for (int mf = 0; mf < 2; ++mf) {
#pragma unroll
    for (int i = 0; i < 16; ++i) {
      float best = fmaxf(acc[mf][0][i], acc[mf][1][i]);
      best = fmaxf(best, __shfl_xor(best, 1));
      best = fmaxf(best, __shfl_xor(best, 2));
      best = fmaxf(best, __shfl_xor(best, 4));
      best = fmaxf(best, __shfl_xor(best, 8));
      best = fmaxf(best, __shfl_xor(best, 16));
      if (l31 == 0) {
        int row = wy * 64 + mf * 32 + (i & 3) + 8 * (i >> 2) + 4 * lh;
        s_max[wx * 128 + row] = best;   // each entry written exactly once
      }
    }
  }
  __syncthreads();
  if (tid < 128) {
    float m = fmaxf(s_max[tid], s_max[128 + tid]);
    atomicMax(&part[row_base + tid], enc_f32(m));
  }
}

// ---------------------------------------------------------------- K5: decode + loss (fp32 scalar out)
__global__ void finish_kernel(const u32* __restrict__ part, float* __restrict__ out) {
  float v = 0.f;
  for (int i = threadIdx.x; i < NPIX; i += 1024) {
    v += 1.0f - dec_f32(part[i]);
  }
#pragma unroll
  for (int off = 32; off > 0; off >>= 1) v += __shfl_down(v, off);
  __shared__ float red[16];
  int w = threadIdx.x >> 6;
  if ((threadIdx.x & 63) == 0) red[w] = v;
  __syncthreads();
  if (threadIdx.x == 0) {
    float s = 0.f;
#pragma unroll
    for (int k = 0; k < 16; ++k) s += red[k];
    out[0] = s * (1.0f / (float)NPIX);
  }
}

// ---------------------------------------------------------------- launcher
extern "C" void kernel_launch(void* const* d_in, const int* in_sizes, int n_in,
                              void* d_out, int out_size, void* d_ws, size_t ws_size,
                              hipStream_t stream) {
  const float* x = (const float*)d_in[0];
  const float* s = (const float*)d_in[1];
  char* ws = (char*)d_ws;
  float* pa   = (float*)(ws + 0);         //   401408
  float* pb   = (float*)(ws + 401408);    //   401408
  float* ra   = (float*)(ws + 802816);    //    50176
  float* rb   = (float*)(ws + 852992);    //    50176
  u32*   part = (u32*)  (ws + 903168);    //    50176 (encoded row maxima)
  u8*    Ar   = (u8*)   (ws + 953344);    //  9633792
  u8*    Br   = (u8*)   (ws + 10587136);  //  9633792  -> total 20220928 B

  colsumsq_kernel<<<dim3(49, 8), 256, 0, stream>>>(x, s, pa, pb);
  rnorm_kernel<<<49, 256, 0, stream>>>(pa, pb, ra, rb, part);
  transpose_kernel<<<dim3(392, 24, 2), 256, 0, stream>>>(x, s, ra, rb, Ar, Br);
  gemm_max_kernel<<<dim3(8, 13, 98), 256, 0, stream>>>(Ar, Br, part);
  finish_kernel<<<1, 1024, 0, stream>>>(part, (float*)d_out);
}

// Round 8
// 699.378 us; speedup vs baseline: 2.1345x; 1.1052x over previous
//
#include <hip/hip_runtime.h>
#include <hip/hip_bf16.h>

typedef unsigned char u8;
typedef unsigned short u16;
typedef unsigned int u32;
typedef __attribute__((ext_vector_type(4))) int intx4;
typedef __attribute__((ext_vector_type(8))) int intx8;
typedef __attribute__((ext_vector_type(4))) float floatx4;
typedef __attribute__((ext_vector_type(16))) float floatx16;

#define NPIX 12544   // 112*112 = 98 * 128
#define KDIM 768     // channels; fp8 row = 768 B
#define EPSF 1e-8f
#define SCALE1 0x7F7F7F7FU  // E8M0 = 127 -> 2^0 = 1.0 in every byte

// ---------------------------------------------------------------- async G->LDS
__device__ __forceinline__ void gload_lds16(const void* g, void* l) {
  __builtin_amdgcn_global_load_lds(
      (const __attribute__((address_space(1))) void*)g,
      (__attribute__((address_space(3))) void*)l, 16, 0, 0);
}

// sortable-uint encoding of float (monotone): max over enc == max over float
__device__ __forceinline__ u32 enc_f32(float f) {
  u32 u = __float_as_uint(f);
  return (u & 0x80000000u) ? ~u : (u | 0x80000000u);
}
__device__ __forceinline__ float dec_f32(u32 e) {
  u32 u = (e & 0x80000000u) ? (e & 0x7FFFFFFFu) : ~e;
  return __uint_as_float(u);
}

// lo/hi 16B halves -> one 32B fragment without elementwise copies
union frag32 {
  intx8 v;
  struct { intx4 lo, hi; } p;
};

// ---------------------------------------------------------------- K1: column sum-of-squares partials
__global__ void colsumsq_kernel(const float* __restrict__ a, const float* __restrict__ b,
                                float* __restrict__ pa, float* __restrict__ pb) {
  int i = blockIdx.x * 256 + threadIdx.x;
  int c0 = blockIdx.y * 96;
  float sa = 0.f, sb = 0.f;
#pragma unroll 4
  for (int c = c0; c < c0 + 96; ++c) {
    float va = a[(size_t)c * NPIX + i];
    float vb = b[(size_t)c * NPIX + i];
    sa += va * va;
    sb += vb * vb;
  }
  pa[(size_t)blockIdx.y * NPIX + i] = sa;
  pb[(size_t)blockIdx.y * NPIX + i] = sb;
}

// ---------------------------------------------------------------- K2: 1/(sqrt(sum+eps)+eps) + zero atomic-max buffer
__global__ void rnorm_kernel(const float* __restrict__ pa, const float* __restrict__ pb,
                             float* __restrict__ ra, float* __restrict__ rb,
                             u32* __restrict__ part) {
  int i = blockIdx.x * 256 + threadIdx.x;
  float sa = 0.f, sb = 0.f;
#pragma unroll
  for (int c = 0; c < 8; ++c) {
    sa += pa[(size_t)c * NPIX + i];
    sb += pb[(size_t)c * NPIX + i];
  }
  ra[i] = 1.f / (sqrtf(sa + EPSF) + EPSF);
  rb[i] = 1.f / (sqrtf(sb + EPSF) + EPSF);
  part[i] = 0u;
}

// ---------------------------------------------------------------- K3: transpose + normalize + fp8 e4m3 pack
__global__ void transpose_kernel(const float* __restrict__ a, const float* __restrict__ b,
                                 const float* __restrict__ ra, const float* __restrict__ rb,
                                 u8* __restrict__ Ar, u8* __restrict__ Br) {
  const float* src = blockIdx.z ? b : a;
  const float* rn  = blockIdx.z ? rb : ra;
  u8* dst          = blockIdx.z ? Br : Ar;
  __shared__ float tile[32][33];
  int i0 = blockIdx.x * 32;
  int c0 = blockIdx.y * 32;
  int tx = threadIdx.x & 31;
  int ty = threadIdx.x >> 5;
#pragma unroll
  for (int d = 0; d < 4; ++d) {
    int c = c0 + ty + d * 8;
    tile[ty + d * 8][tx] = src[(size_t)c * NPIX + i0 + tx];
  }
  __syncthreads();
  int pl = threadIdx.x >> 3;
  int cq = threadIdx.x & 7;
  int gi = i0 + pl;
  float r = rn[gi];
  float v0 = tile[cq * 4 + 0][pl] * r;
  float v1 = tile[cq * 4 + 1][pl] * r;
  float v2 = tile[cq * 4 + 2][pl] * r;
  float v3 = tile[cq * 4 + 3][pl] * r;
  int p = __builtin_amdgcn_cvt_pk_fp8_f32(v0, v1, 0, false);
  p = __builtin_amdgcn_cvt_pk_fp8_f32(v2, v3, p, true);
  *(u32*)&dst[(size_t)gi * KDIM + c0 + cq * 4] = (u32)p;
}

// ---------------------------------------------------------------- K4: 128x128 tile per block, MX-fp8 32x32x64
// Wave (wx,wy) computes 64x64 as 2x2 tiles of 32x32 (K=64 per mfma).
// LDS (per matrix, 16 KB): 8 regions of 2048 B = (32-row group rg, k64 block kb).
// Byte (row r, k: h=k>>5, c=(k>>4)&1, j=k&15) at region + c*1024 + (h*32+r)*16 + j.
// A-operand layout: lane = (k-half = lane>>5, row = lane&31), 32 contiguous
// K-bytes/lane -> each frag b128 is the identity permutation over one
// contiguous 1024 B region (R6/R7-verified zero-conflict property).
// NOTE: no min-waves launch bound — R5/R6/R7 showed any cap makes the
// allocator split the unified file 50/50 and scratch-spill the arch half
// (WRITE_SIZE in GBs). R4 (uncapped) was the only no-spill config.
__global__ __launch_bounds__(256) void gemm_max_kernel(const u8* __restrict__ Ar,
                                                       const u8* __restrict__ Br,
                                                       u32* __restrict__ part) {
  const int X = blockIdx.x;
  const int t13 = blockIdx.y;
  const int live = (X < 2) ? 13 : 12;
  if (t13 >= live) return;
  const int ct = (X < 2) ? (X * 13 + t13) : (X * 12 + 2 + t13);
  const int rt = blockIdx.z;

  __shared__ alignas(16) u8 As[16384];
  __shared__ alignas(16) u8 Bs[16384];
  __shared__ float s_max[2 * 128];

  const int tid = threadIdx.x;
  const int wave = tid >> 6;
  const int lane = tid & 63;
  const int wx = wave & 1;
  const int wy = wave >> 1;
  const int lh = lane >> 5;
  const int l31 = lane & 31;

  const int row_base = rt * 128;
  const int col_base = ct * 128;

  const u8* gA = Ar + (size_t)row_base * KDIM;
  const u8* gB = Br + (size_t)col_base * KDIM;

  // staging: instr t writes LDS bytes D = t*4096 + tid*16; decode D ->
  // region = D>>11 (rg = D>>12, kb = (D>>11)&1), w = D&2047:
  // c = w>>10, h*32+r = (w>>4)&63
  int soff[4];
#pragma unroll
  for (int t = 0; t < 4; ++t) {
    int D = t * 4096 + tid * 16;
    int rg = D >> 12;
    int kb = (D >> 11) & 1;
    int w = D & 2047;
    int c = w >> 10;
    int hr = (w >> 4) & 63;
    int h = hr >> 5;
    int r = hr & 31;
    soff[t] = (rg * 32 + r) * KDIM + kb * 64 + h * 32 + c * 16;
  }

  // fragment per-lane bases; offsets: mf/nf*4096 + s*2048 + {0,1024}
  const u8* aP = &As[wy * 8192 + lane * 16];
  const u8* bP = &Bs[wx * 8192 + lane * 16];

  floatx16 acc[2][2];
#pragma unroll
  for (int mf = 0; mf < 2; ++mf)
#pragma unroll
    for (int nf = 0; nf < 2; ++nf)
#pragma unroll
      for (int i = 0; i < 16; ++i) acc[mf][nf][i] = 0.f;

  for (int k0 = 0; k0 < KDIM; k0 += 128) {
    __syncthreads();
#pragma unroll
    for (int t = 0; t < 4; ++t) {
      gload_lds16(gA + soff[t] + k0, &As[t * 4096 + tid * 16]);
      gload_lds16(gB + soff[t] + k0, &Bs[t * 4096 + tid * 16]);
    }
    __syncthreads();

#pragma unroll
    for (int s = 0; s < 2; ++s) {
      frag32 af[2];
#pragma unroll
      for (int mf = 0; mf < 2; ++mf) {
        af[mf].p.lo = *(const intx4*)(aP + mf * 4096 + s * 2048);
        af[mf].p.hi = *(const intx4*)(aP + mf * 4096 + s * 2048 + 1024);
      }
#pragma unroll
      for (int nf = 0; nf < 2; ++nf) {
        frag32 bf;
        bf.p.lo = *(const intx4*)(bP + nf * 4096 + s * 2048);
        bf.p.hi = *(const intx4*)(bP + nf * 4096 + s * 2048 + 1024);
#pragma unroll
        for (int mf = 0; mf < 2; ++mf)
          acc[mf][nf] = __builtin_amdgcn_mfma_scale_f32_32x32x64_f8f6f4(
              af[mf].v, bf.v, acc[mf][nf], 0, 0, 0, SCALE1, 0, SCALE1);
      }
    }
  }

  // epilogue: per-row max. 32x32 C/D layout: col = lane&31,
  // row = (reg&3) + 8*(reg>>2) + 4*(lane>>5).
#pragma unroll
  for (int mf = 0; mf < 2; ++mf) {
#pragma unroll
    for (int i = 0; i < 16; ++i) {
      float best = fmaxf(acc[mf][0][i], acc[mf][1][i]);
      best = fmaxf(best, __shfl_xor(best, 1));
      best = fmaxf(best, __shfl_xor(best, 2));
      best = fmaxf(best, __shfl_xor(best, 4));
      best = fmaxf(best, __shfl_xor(best, 8));
      best = fmaxf(best, __shfl_xor(best, 16));
      if (l31 == 0) {
        int row = wy * 64 + mf * 32 + (i & 3) + 8 * (i >> 2) + 4 * lh;
        s_max[wx * 128 + row] = best;   // each entry written exactly once
      }
    }
  }
  __syncthreads();
  if (tid < 128) {
    float m = fmaxf(s_max[tid], s_max[128 + tid]);
    atomicMax(&part[row_base + tid], enc_f32(m));
  }
}

// ---------------------------------------------------------------- K5: decode + loss (fp32 scalar out)
__global__ void finish_kernel(const u32* __restrict__ part, float* __restrict__ out) {
  float v = 0.f;
  for (int i = threadIdx.x; i < NPIX; i += 1024) {
    v += 1.0f - dec_f32(part[i]);
  }
#pragma unroll
  for (int off = 32; off > 0; off >>= 1) v += __shfl_down(v, off);
  __shared__ float red[16];
  int w = threadIdx.x >> 6;
  if ((threadIdx.x & 63) == 0) red[w] = v;
  __syncthreads();
  if (threadIdx.x == 0) {
    float s = 0.f;
#pragma unroll
    for (int k = 0; k < 16; ++k) s += red[k];
    out[0] = s * (1.0f / (float)NPIX);
  }
}

// ---------------------------------------------------------------- launcher
extern "C" void kernel_launch(void* const* d_in, const int* in_sizes, int n_in,
                              void* d_out, int out_size, void* d_ws, size_t ws_size,
                              hipStream_t stream) {
  const float* x = (const float*)d_in[0];
  const float* s = (const float*)d_in[1];
  char* ws = (char*)d_ws;
  float* pa   = (float*)(ws + 0);         //   401408
  float* pb   = (float*)(ws + 401408);    //   401408
  float* ra   = (float*)(ws + 802816);    //    50176
  float* rb   = (float*)(ws + 852992);    //    50176
  u32*   part = (u32*)  (ws + 903168);    //    50176 (encoded row maxima)
  u8*    Ar   = (u8*)   (ws + 953344);    //  9633792
  u8*    Br   = (u8*)   (ws + 10587136);  //  9633792  -> total 20220928 B

  colsumsq_kernel<<<dim3(49, 8), 256, 0, stream>>>(x, s, pa, pb);
  rnorm_kernel<<<49, 256, 0, stream>>>(pa, pb, ra, rb, part);
  transpose_kernel<<<dim3(392, 24, 2), 256, 0, stream>>>(x, s, ra, rb, Ar, Br);
  gemm_max_kernel<<<dim3(8, 13, 98), 256, 0, stream>>>(Ar, Br, part);
  finish_kernel<<<1, 1024, 0, stream>>>(part, (float*)d_out);
}